// Round 1
// baseline (3852.179 us; speedup 1.0000x reference)
//
#include <hip/hip_runtime.h>
#include <hip/hip_fp16.h>

// Workspace requirement: 3 * 134217728 B = 402,653,184 B (384 MiB).
// Layout (lifetime-aliased):
//   [0,128M):    q (f32)      -> later qk (f32)
//   [128M,256M): qT (f32)     -> later vT (fp16, 64M)
//   [256M,384M): k (f32)      -> later P (fp16, 64M) + v (fp16, 64M)

using half4_t = __attribute__((ext_vector_type(4))) _Float16;
using half8_t = __attribute__((ext_vector_type(8))) _Float16;
using f32x4   = __attribute__((ext_vector_type(4))) float;

static constexpr int NB = 8;       // batch
static constexpr int Sd = 2048;    // S == D
static constexpr long MAT = (long)Sd * Sd;

// ---------------------------------------------------------------------------
// Staging: 128 rows x 64 cols tile -> swizzled LDS fp16 (hi [+ lo if SPLIT]).
// f32 source: convert (with scale) to hi fp16 and residual lo fp16.
// Swizzle: halfs offset = row*64 + (col ^ ((row&7)<<3))  (16B-granular XOR).
// ---------------------------------------------------------------------------
template<bool SPLIT, typename T>
__device__ inline void stage_tile(const T* __restrict__ src, int ld, float scl,
                                  _Float16* hi, _Float16* lo, int t)
{
  if constexpr (sizeof(T) == 4) {
#pragma unroll
    for (int c = 0; c < 8; c++) {
      int id  = c * 256 + t;          // 2048 float4 chunks
      int row = id >> 4;              // 16 chunks per row
      int col = (id & 15) << 2;
      f32x4 x = *(const f32x4*)(src + (size_t)row * ld + col);
      half4_t h, l4;
#pragma unroll
      for (int j = 0; j < 4; j++) {
        float xs = x[j] * scl;
        _Float16 hh = (_Float16)xs;
        h[j] = hh;
        if constexpr (SPLIT) l4[j] = (_Float16)(xs - (float)hh);
      }
      int off = row * 64 + (col ^ ((row & 7) << 3));
      *(half4_t*)(hi + off) = h;
      if constexpr (SPLIT) *(half4_t*)(lo + off) = l4;
    }
  } else {
#pragma unroll
    for (int c = 0; c < 4; c++) {
      int id  = c * 256 + t;          // 1024 16B chunks
      int row = id >> 3;              // 8 chunks per row
      int col = (id & 7) << 3;
      half8_t x = *(const half8_t*)(src + (size_t)row * ld + col);
      int off = row * 64 + (col ^ ((row & 7) << 3));
      *(half8_t*)(hi + off) = x;
    }
  }
}

// ---------------------------------------------------------------------------
// GEMM (B^T form): C[i][j] = cscale * sum_k A[i][k]*B[j][k]  (+ bias[j])
// A: [M x K] row-major per batch, B: [N x K] row-major per batch.
// SPLIT: A,B f32 split into hi/lo fp16; acc += Ah*Bh + Al*Bh + Ah*Bl.
// Tile 128x128, BK=64, 4 waves (2x2 of 64x64), 16x16x32 f16 MFMA.
// ---------------------------------------------------------------------------
template<bool SPLIT, bool BIAS, typename AT, typename BT, typename CT>
__global__ __launch_bounds__(256) void gemm_bt(
    const AT* __restrict__ A, long sA, float ascale,
    const BT* __restrict__ B, long sB, float bscale,
    const float* __restrict__ bias, float cscale,
    CT* __restrict__ C, long sC,
    int M, int N, int K)
{
  __shared__ _Float16 Ah[128 * 64];
  __shared__ _Float16 Bh[128 * 64];
  __shared__ _Float16 Al[SPLIT ? 128 * 64 : 8];
  __shared__ _Float16 Bl[SPLIT ? 128 * 64 : 8];

  const int t = threadIdx.x;
  const AT* Ab = A + (size_t)blockIdx.z * sA + (size_t)blockIdx.y * 128 * K;
  const BT* Bp = B + (size_t)blockIdx.z * sB + (size_t)blockIdx.x * 128 * K;
  CT* Cb = C + (size_t)blockIdx.z * sC;

  f32x4 acc[4][4] = {};

  const int w  = t >> 6, l = t & 63;
  const int wm = (w >> 1) * 64, wn = (w & 1) * 64;
  const int lm = l & 15, lk = l >> 4;

  for (int k0 = 0; k0 < K; k0 += 64) {
    stage_tile<SPLIT>(Ab + k0, K, ascale, Ah, Al, t);
    stage_tile<SPLIT>(Bp + k0, K, bscale, Bh, Bl, t);
    __syncthreads();
#pragma unroll
    for (int kk = 0; kk < 2; kk++) {
      const int kh = kk * 32 + lk * 8;
      half8_t ah[4], bh[4], al[4], bl[4];
#pragma unroll
      for (int f = 0; f < 4; f++) {
        int ra = wm + f * 16 + lm;
        int rb = wn + f * 16 + lm;
        int oa = ra * 64 + (kh ^ ((ra & 7) << 3));
        int ob = rb * 64 + (kh ^ ((rb & 7) << 3));
        ah[f] = *(const half8_t*)&Ah[oa];
        bh[f] = *(const half8_t*)&Bh[ob];
        if constexpr (SPLIT) {
          al[f] = *(const half8_t*)&Al[oa];
          bl[f] = *(const half8_t*)&Bl[ob];
        }
      }
#pragma unroll
      for (int fm = 0; fm < 4; fm++)
#pragma unroll
        for (int fn = 0; fn < 4; fn++) {
          acc[fm][fn] = __builtin_amdgcn_mfma_f32_16x16x32_f16(ah[fm], bh[fn], acc[fm][fn], 0, 0, 0);
          if constexpr (SPLIT) {
            acc[fm][fn] = __builtin_amdgcn_mfma_f32_16x16x32_f16(al[fm], bh[fn], acc[fm][fn], 0, 0, 0);
            acc[fm][fn] = __builtin_amdgcn_mfma_f32_16x16x32_f16(ah[fm], bl[fn], acc[fm][fn], 0, 0, 0);
          }
        }
    }
    __syncthreads();
  }

  // C/D layout (m89-verified): col = lane&15, row = (lane>>4)*4 + reg
#pragma unroll
  for (int fm = 0; fm < 4; fm++)
#pragma unroll
    for (int fn = 0; fn < 4; fn++)
#pragma unroll
      for (int r = 0; r < 4; r++) {
        int m = blockIdx.y * 128 + wm + fm * 16 + lk * 4 + r;
        int n = blockIdx.x * 128 + wn + fn * 16 + lm;
        float v = acc[fm][fn][r] * cscale;
        if constexpr (BIAS) v += bias[n];
        Cb[(size_t)m * N + n] = (CT)v;
      }
}

// ---------------------------------------------------------------------------
// Per-batch 2048x2048 transpose via 64x64 LDS tile (+1 pad).
// ---------------------------------------------------------------------------
template<typename T>
__global__ __launch_bounds__(256) void transpose_sq(const T* __restrict__ in,
                                                    T* __restrict__ out)
{
  __shared__ T tile[64][65];
  const T* ib = in + (size_t)blockIdx.z * MAT;
  T* ob = out + (size_t)blockIdx.z * MAT;
  const int tx = threadIdx.x & 63, ty = threadIdx.x >> 6;
  const int bx = blockIdx.x * 64, by = blockIdx.y * 64;
#pragma unroll
  for (int i = 0; i < 16; i++) {
    int r = ty + i * 4;
    tile[r][tx] = ib[(size_t)(by + r) * Sd + bx + tx];
  }
  __syncthreads();
#pragma unroll
  for (int i = 0; i < 16; i++) {
    int r = ty + i * 4;
    ob[(size_t)(bx + r) * Sd + by + tx] = tile[tx][r];
  }
}

// ---------------------------------------------------------------------------
// Row softmax: one 256-thread block per row of 2048 f32 -> fp16 probs.
// ---------------------------------------------------------------------------
__global__ __launch_bounds__(256) void softmax_rows(const float* __restrict__ X,
                                                    _Float16* __restrict__ P)
{
  __shared__ float red[4];
  const size_t row = blockIdx.x;
  const float* x = X + row * Sd;
  _Float16* p = P + row * Sd;
  const int t = threadIdx.x;
  float v[8];
  float mx = -1e30f;
#pragma unroll
  for (int i = 0; i < 8; i++) { v[i] = x[t + 256 * i]; mx = fmaxf(mx, v[i]); }
#pragma unroll
  for (int o = 32; o > 0; o >>= 1) mx = fmaxf(mx, __shfl_xor(mx, o, 64));
  if ((t & 63) == 0) red[t >> 6] = mx;
  __syncthreads();
  mx = fmaxf(fmaxf(red[0], red[1]), fmaxf(red[2], red[3]));
  __syncthreads();   // protect red[] reuse
  float s = 0.f;
#pragma unroll
  for (int i = 0; i < 8; i++) { v[i] = __expf(v[i] - mx); s += v[i]; }
#pragma unroll
  for (int o = 32; o > 0; o >>= 1) s += __shfl_xor(s, o, 64);
  if ((t & 63) == 0) red[t >> 6] = s;
  __syncthreads();
  s = red[0] + red[1] + red[2] + red[3];
  float inv = 1.f / s;
#pragma unroll
  for (int i = 0; i < 8; i++) p[t + 256 * i] = (_Float16)(v[i] * inv);
}

// ---------------------------------------------------------------------------
extern "C" void kernel_launch(void* const* d_in, const int* in_sizes, int n_in,
                              void* d_out, int out_size, void* d_ws, size_t ws_size,
                              hipStream_t stream)
{
  const float* query = (const float*)d_in[0];
  const float* key_  = (const float*)d_in[1];
  const float* value = (const float*)d_in[2];
  const float* Wq = (const float*)d_in[3];
  const float* bq = (const float*)d_in[4];
  const float* Wk = (const float*)d_in[5];
  const float* bk = (const float*)d_in[6];
  const float* Wv = (const float*)d_in[7];
  const float* bv = (const float*)d_in[8];
  float* out = (float*)d_out;

  char* ws = (char*)d_ws;
  const size_t MB128 = (size_t)NB * MAT * 4;        // 134,217,728 B
  float*    q   = (float*)(ws);
  float*    qk  = (float*)(ws);                     // aliases q (dead by then)
  float*    qT  = (float*)(ws + MB128);
  _Float16* vT  = (_Float16*)(ws + MB128);          // aliases qT (dead after QK)
  float*    kpr = (float*)(ws + 2 * MB128);
  _Float16* P   = (_Float16*)(ws + 2 * MB128);      // aliases k (dead after QK)
  _Float16* vpr = (_Float16*)(ws + 2 * MB128 + MB128 / 2);

  dim3 blk(256);
  dim3 gg(16, 16, NB);   // (N/128, M/128, batch)
  dim3 gt(32, 32, NB);

  // 1. q = query @ Wq^T + bq  (split-fp16, W scaled x32 to keep lo normal)
  gemm_bt<true, true, float, float, float><<<gg, blk, 0, stream>>>(
      query, MAT, 1.0f, Wq, 0, 32.0f, bq, 1.0f / 32.0f, q, MAT, Sd, Sd, Sd);
  // 2. qT[b] = q[b]^T
  transpose_sq<float><<<gt, blk, 0, stream>>>(q, qT);
  // 3. k = key_ @ Wk^T + bk
  gemm_bt<true, true, float, float, float><<<gg, blk, 0, stream>>>(
      key_, MAT, 1.0f, Wk, 0, 32.0f, bk, 1.0f / 32.0f, kpr, MAT, Sd, Sd, Sd);
  // 4. qk[b][e][s'] = sum_m qT[b][e][m] * k[b][s'][m]  (split, x16 each side)
  gemm_bt<true, false, float, float, float><<<gg, blk, 0, stream>>>(
      qT, MAT, 16.0f, kpr, MAT, 16.0f, nullptr, 1.0f / 256.0f, qk, MAT, Sd, Sd, Sd);
  // 5. P = row-softmax(qk) in fp16
  softmax_rows<<<dim3(NB * Sd), blk, 0, stream>>>(qk, P);
  // 6. v = value @ Wv^T + bv  (plain fp16)
  gemm_bt<false, true, float, float, _Float16><<<gg, blk, 0, stream>>>(
      value, MAT, 1.0f, Wv, 0, 1.0f, bv, 1.0f, vpr, MAT, Sd, Sd, Sd);
  // 7. vT[b] = v[b]^T
  transpose_sq<_Float16><<<gt, blk, 0, stream>>>(vpr, vT);
  // 8. out[b][d'][e] = sum_s' vT[b][d'][s'] * P[b][e][s']
  gemm_bt<false, false, _Float16, _Float16, float><<<gg, blk, 0, stream>>>(
      vT, MAT, 1.0f, P, MAT, 1.0f, nullptr, 1.0f, out, MAT, Sd, Sd, Sd);
}

// Round 2
// 1531.386 us; speedup vs baseline: 2.5155x; 2.5155x over previous
//
#include <hip/hip_runtime.h>
#include <hip/hip_fp16.h>

// Workspace: 384 MiB, same as round 1.
//   A [0,128M):   q_h/l (fp16)  -> k_h/l (fp16)  -> qk (f32)
//   D [128,256M): qT_h/l        -> P (fp16, 64M) + vT (fp16, 64M)
//   E [256,384M): kk_h/l        -> value_h (fp16, 64M)
// d_out scratch (dead before final GEMM writes it):
//   [0,16M) wq_h/l, [16,32M) wk_h/l, [32,40M) wv_h

using half4_t = __attribute__((ext_vector_type(4))) _Float16;
using half8_t = __attribute__((ext_vector_type(8))) _Float16;
using f32x4   = __attribute__((ext_vector_type(4))) float;

static constexpr int NB = 8;
static constexpr int Sd = 2048;
static constexpr long MAT = (long)Sd * Sd;

__device__ __forceinline__ void gload16(const _Float16* g, _Float16* l) {
  __builtin_amdgcn_global_load_lds(
      (const __attribute__((address_space(1))) void*)g,
      (__attribute__((address_space(3))) void*)l, 16, 0, 0);
}

// ---------------------------------------------------------------------------
// Elementwise f32 -> fp16 hi (+ residual lo), scaled. 8 elems/thread/iter.
// ---------------------------------------------------------------------------
template<bool SPLIT>
__global__ __launch_bounds__(256) void presplit(const float* __restrict__ in,
    _Float16* __restrict__ h, _Float16* __restrict__ l, long n8, float scl)
{
  long i = (long)blockIdx.x * 256 + threadIdx.x;
  const long stride = (long)gridDim.x * 256;
  for (; i < n8; i += stride) {
    const f32x4* p = (const f32x4*)(in + i * 8);
    f32x4 a = p[0], b = p[1];
    half8_t hh, ll;
#pragma unroll
    for (int j = 0; j < 4; j++) {
      float x = a[j] * scl; _Float16 hv = (_Float16)x;
      hh[j] = hv; if constexpr (SPLIT) ll[j] = (_Float16)(x - (float)hv);
      float y = b[j] * scl; _Float16 hw = (_Float16)y;
      hh[4 + j] = hw; if constexpr (SPLIT) ll[4 + j] = (_Float16)(y - (float)hw);
    }
    *(half8_t*)(h + i * 8) = hh;
    if constexpr (SPLIT) *(half8_t*)(l + i * 8) = ll;
  }
}

// ---------------------------------------------------------------------------
// GEMM (B^T form): C[i][j] = cscale * sum_k A[i][k]*B[j][k]  (+ bias)
// Operands pre-split fp16 (hi + lo) in global; staging via global_load_lds
// with pre-swizzled source (slot s -> s^(row&7)), swizzled ds_read.
// Tile 128x128, BK=64, 4 waves, 16x16x32 f16 MFMA. XCD-aware block swizzle.
// SPLIT: acc += Ah*Bh + Al*Bh + Ah*Bl (operands carry x16 scale each).
// BIAS: 0 none, 1 bias[n] (col), 2 bias[m] (row).
// OUT:  0 f32, 1 fp16, 2 split fp16 hi/lo (x16).
// ---------------------------------------------------------------------------
template<int SPLIT, int BIAS, int OUT>
__global__ __launch_bounds__(256, 2) void gemm2(
    const _Float16* __restrict__ Ah, const _Float16* __restrict__ Al, long sA,
    const _Float16* __restrict__ Bh, const _Float16* __restrict__ Bl, long sB,
    const float* __restrict__ bias, float cscale,
    void* __restrict__ Cp, void* __restrict__ Clp, long sC)
{
  constexpr int K = Sd, N = Sd;
  __shared__ _Float16 As[128 * 64];
  __shared__ _Float16 Bs[128 * 64];
  __shared__ _Float16 Als[SPLIT ? 128 * 64 : 8];
  __shared__ _Float16 Bls[SPLIT ? 128 * 64 : 8];

  // XCD swizzle: nwg = 2048, 256 consecutive per XCD (one batch per XCD)
  const int wg  = blockIdx.x;
  const int swz = (wg & 7) * 256 + (wg >> 3);
  const int bz  = swz >> 8;
  const int rem = swz & 255;
  const int by  = rem >> 4, bx = rem & 15;

  const int t = threadIdx.x, w = t >> 6, l = t & 63;

  const _Float16* Ab = Ah + (size_t)bz * sA + (size_t)(by * 128) * K;
  const _Float16* Bb = Bh + (size_t)bz * sB + (size_t)(bx * 128) * K;
  const _Float16* Abl = nullptr; const _Float16* Bbl = nullptr;
  if constexpr (SPLIT) {
    Abl = Al + (size_t)bz * sA + (size_t)(by * 128) * K;
    Bbl = Bl + (size_t)bz * sB + (size_t)(bx * 128) * K;
  }

  // staging geometry: wave w stages rows [32w, 32w+32); 4 issues of 8 rows.
  // lane l -> row +（l>>3), dest slot (l&7); source slot = (l&7)^(l>>3).
  const size_t lane_off = (size_t)(w * 32 + (l >> 3)) * K + (size_t)(((l & 7) ^ (l >> 3)) * 8);

  f32x4 acc[4][4] = {};
  const int wm = (w >> 1) * 64, wn = (w & 1) * 64;
  const int lm = l & 15, lk = l >> 4;

  for (int k0 = 0; k0 < K; k0 += 64) {
#pragma unroll
    for (int i = 0; i < 4; i++) {
      const size_t go = lane_off + (size_t)(8 * i) * K + k0;
      const int lo = (w * 32 + 8 * i) * 64;
      gload16(Ab + go, &As[lo]);
      gload16(Bb + go, &Bs[lo]);
      if constexpr (SPLIT) {
        gload16(Abl + go, &Als[lo]);
        gload16(Bbl + go, &Bls[lo]);
      }
    }
    __syncthreads();
#pragma unroll
    for (int kk = 0; kk < 2; kk++) {
      const int kh = kk * 32 + lk * 8;
      half8_t ah[4], bh[4], al[4], bl[4];
#pragma unroll
      for (int f = 0; f < 4; f++) {
        int ra = wm + f * 16 + lm;
        int rb = wn + f * 16 + lm;
        int oa = ra * 64 + (kh ^ ((ra & 7) << 3));
        int ob = rb * 64 + (kh ^ ((rb & 7) << 3));
        ah[f] = *(const half8_t*)&As[oa];
        bh[f] = *(const half8_t*)&Bs[ob];
        if constexpr (SPLIT) {
          al[f] = *(const half8_t*)&Als[oa];
          bl[f] = *(const half8_t*)&Bls[ob];
        }
      }
#pragma unroll
      for (int fm = 0; fm < 4; fm++)
#pragma unroll
        for (int fn = 0; fn < 4; fn++) {
          acc[fm][fn] = __builtin_amdgcn_mfma_f32_16x16x32_f16(ah[fm], bh[fn], acc[fm][fn], 0, 0, 0);
          if constexpr (SPLIT) {
            acc[fm][fn] = __builtin_amdgcn_mfma_f32_16x16x32_f16(al[fm], bh[fn], acc[fm][fn], 0, 0, 0);
            acc[fm][fn] = __builtin_amdgcn_mfma_f32_16x16x32_f16(ah[fm], bl[fn], acc[fm][fn], 0, 0, 0);
          }
        }
    }
    __syncthreads();
  }

  // C/D layout: col = lane&15, row = (lane>>4)*4 + reg
#pragma unroll
  for (int fm = 0; fm < 4; fm++)
#pragma unroll
    for (int fn = 0; fn < 4; fn++)
#pragma unroll
      for (int r = 0; r < 4; r++) {
        int m = by * 128 + wm + fm * 16 + lk * 4 + r;
        int n = bx * 128 + wn + fn * 16 + lm;
        float v = acc[fm][fn][r] * cscale;
        if constexpr (BIAS == 1) v += bias[n];
        if constexpr (BIAS == 2) v += bias[m];
        size_t cidx = (size_t)bz * sC + (size_t)m * N + n;
        if constexpr (OUT == 0) ((float*)Cp)[cidx] = v;
        else if constexpr (OUT == 1) ((_Float16*)Cp)[cidx] = (_Float16)v;
        else {
          float sv = v * 16.0f;
          _Float16 hv = (_Float16)sv;
          ((_Float16*)Cp)[cidx]  = hv;
          ((_Float16*)Clp)[cidx] = (_Float16)(sv - (float)hv);
        }
      }
}

// ---------------------------------------------------------------------------
// Row softmax: one 256-thread block per row of 2048 f32 -> fp16 probs.
// ---------------------------------------------------------------------------
__global__ __launch_bounds__(256) void softmax_rows(const float* __restrict__ X,
                                                    _Float16* __restrict__ P)
{
  __shared__ float red[4];
  const size_t row = blockIdx.x;
  const float* x = X + row * Sd;
  _Float16* p = P + row * Sd;
  const int t = threadIdx.x;
  float v[8];
  float mx = -1e30f;
#pragma unroll
  for (int i = 0; i < 8; i++) { v[i] = x[t + 256 * i]; mx = fmaxf(mx, v[i]); }
#pragma unroll
  for (int o = 32; o > 0; o >>= 1) mx = fmaxf(mx, __shfl_xor(mx, o, 64));
  if ((t & 63) == 0) red[t >> 6] = mx;
  __syncthreads();
  mx = fmaxf(fmaxf(red[0], red[1]), fmaxf(red[2], red[3]));
  __syncthreads();
  float s = 0.f;
#pragma unroll
  for (int i = 0; i < 8; i++) { v[i] = __expf(v[i] - mx); s += v[i]; }
#pragma unroll
  for (int o = 32; o > 0; o >>= 1) s += __shfl_xor(s, o, 64);
  if ((t & 63) == 0) red[t >> 6] = s;
  __syncthreads();
  s = red[0] + red[1] + red[2] + red[3];
  float inv = 1.f / s;
#pragma unroll
  for (int i = 0; i < 8; i++) p[t + 256 * i] = (_Float16)(v[i] * inv);
}

// ---------------------------------------------------------------------------
extern "C" void kernel_launch(void* const* d_in, const int* in_sizes, int n_in,
                              void* d_out, int out_size, void* d_ws, size_t ws_size,
                              hipStream_t stream)
{
  const float* query = (const float*)d_in[0];
  const float* key_  = (const float*)d_in[1];
  const float* value = (const float*)d_in[2];
  const float* Wq = (const float*)d_in[3];
  const float* bq = (const float*)d_in[4];
  const float* Wk = (const float*)d_in[5];
  const float* bk = (const float*)d_in[6];
  const float* Wv = (const float*)d_in[7];
  const float* bv = (const float*)d_in[8];

  char* ws = (char*)d_ws;
  char* ob = (char*)d_out;
  const size_t M64 = (size_t)NB * MAT * 2;   // 64 MiB (fp16 batch tensor)

  // ws regions
  _Float16* q_h  = (_Float16*)(ws);                 // A[0,64)
  _Float16* q_l  = (_Float16*)(ws + M64);           // A[64,128)
  _Float16* k_h  = q_h;                             // reuse A
  _Float16* k_l  = q_l;
  float*    qk   = (float*)(ws);                    // A as f32 (128M)
  _Float16* qT_h = (_Float16*)(ws + 2 * M64);       // D[128,192)
  _Float16* qT_l = (_Float16*)(ws + 3 * M64);       // D[192,256)
  _Float16* P    = qT_h;                            // D[128,192) after qT dead
  _Float16* vT   = qT_l;                            // D[192,256) after qT dead
  _Float16* kk_h = (_Float16*)(ws + 4 * M64);       // E[256,320)
  _Float16* kk_l = (_Float16*)(ws + 5 * M64);       // E[320,384)
  _Float16* val_h = kk_h;                           // reuse E after G3

  // d_out scratch (dead before final GEMM)
  _Float16* wq_h = (_Float16*)(ob);
  _Float16* wq_l = (_Float16*)(ob + (MAT * 2));
  _Float16* wk_h = (_Float16*)(ob + 2 * (MAT * 2));
  _Float16* wk_l = (_Float16*)(ob + 3 * (MAT * 2));
  _Float16* wv_h = (_Float16*)(ob + 4 * (MAT * 2));
  float* out = (float*)d_out;

  dim3 blk(256);
  dim3 gg(2048);
  const long NQ8 = (long)NB * MAT / 8;
  const long NW8 = MAT / 8;

  // 1. presplit query (x16), Wq (x16)
  presplit<true><<<dim3(2048), blk, 0, stream>>>(query, q_h, q_l, NQ8, 16.f);
  presplit<true><<<dim3(2048), blk, 0, stream>>>(Wq, wq_h, wq_l, NW8, 16.f);
  // 2. qT[e][s] = sum_d Wq[e][d]*query[s][d] + bq[e]  (row bias), split out
  gemm2<1, 2, 2><<<gg, blk, 0, stream>>>(wq_h, wq_l, 0, q_h, q_l, MAT,
                                         bq, 1.f / 256.f, qT_h, qT_l, MAT);
  // 3. presplit key_ (x16), Wk (x16)
  presplit<true><<<dim3(2048), blk, 0, stream>>>(key_, k_h, k_l, NQ8, 16.f);
  presplit<true><<<dim3(2048), blk, 0, stream>>>(Wk, wk_h, wk_l, NW8, 16.f);
  // 4. kk[s'][m] = sum_d key_[s'][d]*Wk[m][d] + bk[m]  (col bias), split out
  gemm2<1, 1, 2><<<gg, blk, 0, stream>>>(k_h, k_l, MAT, wk_h, wk_l, 0,
                                         bk, 1.f / 256.f, kk_h, kk_l, MAT);
  // 5. qk[e][s'] = sum_m qT[e][m]*kk[s'][m]  (f32 out)
  gemm2<1, 0, 0><<<gg, blk, 0, stream>>>(qT_h, qT_l, MAT, kk_h, kk_l, MAT,
                                         nullptr, 1.f / 256.f, qk, nullptr, MAT);
  // 6. P = row-softmax(qk), fp16
  softmax_rows<<<dim3(NB * Sd), blk, 0, stream>>>(qk, P);
  // 7. presplit value (x1, fp16 only), Wv (x1)
  presplit<false><<<dim3(2048), blk, 0, stream>>>(value, val_h, nullptr, NQ8, 1.f);
  presplit<false><<<dim3(2048), blk, 0, stream>>>(Wv, wv_h, nullptr, NW8, 1.f);
  // 8. vT[d'][s'] = sum_d Wv[d'][d]*value[s'][d] + bv[d']  (row bias), fp16
  gemm2<0, 2, 1><<<gg, blk, 0, stream>>>(wv_h, nullptr, 0, val_h, nullptr, MAT,
                                         bv, 1.f, vT, nullptr, MAT);
  // 9. out[d'][e] = sum_s' vT[d'][s']*P[e][s']  (f32 -> d_out)
  gemm2<0, 0, 0><<<gg, blk, 0, stream>>>(vT, nullptr, MAT, P, nullptr, MAT,
                                         nullptr, 1.f, out, nullptr, MAT);
}